// Round 1
// baseline (539.416 us; speedup 1.0000x reference)
//
#include <hip/hip_runtime.h>

#define K 7
#define PAD 3
#define TW 128                 // tile width (pixels)
#define TH 8                   // tile height (pixels)
#define LW (TW + 2 * PAD)      // 134 staged cols
#define LH (TH + 2 * PAD)      // 14 staged rows
#define LSTRIDE (LW + 2)       // 136 floats: keeps rows 8-bank rotated

__global__ __launch_bounds__(256) void adaptive_aggregation_kernel(
    const float* __restrict__ thick,
    const float* __restrict__ thin,
    const float* __restrict__ coeff,
    float* __restrict__ out,
    int H, int W)
{
    __shared__ float sal[LH][LSTRIDE];

    const int b  = blockIdx.z;
    const int h0 = blockIdx.y * TH;
    const int w0 = blockIdx.x * TW;
    const int tx = threadIdx.x;        // 0..31
    const int ty = threadIdx.y;        // 0..7
    const int tid = ty * 32 + tx;      // 0..255
    const int HW = H * W;
    const size_t base1 = (size_t)b * HW;

    // ---- stage sal = max(thick, thin) tile + halo into LDS (zero-padded) ----
    for (int idx = tid; idx < LH * LW; idx += 256) {
        const int lr = idx / LW;
        const int lc = idx - lr * LW;
        const int gh = h0 - PAD + lr;
        const int gw = w0 - PAD + lc;
        float v = 0.0f;
        if (gh >= 0 && gh < H && gw >= 0 && gw < W) {
            const size_t off = base1 + (size_t)gh * W + gw;
            v = fmaxf(thick[off], thin[off]);
        }
        sal[lr][lc] = v;
    }
    __syncthreads();

    // ---- each thread: 4 consecutive output pixels at (h0+ty, w0+tx*4 ..+3) ----
    const int h = h0 + ty;
    const int w = w0 + tx * 4;
    const size_t cbase = (size_t)b * (K * K) * HW + (size_t)h * W + w;

    float acc0 = 0.f, acc1 = 0.f, acc2 = 0.f, acc3 = 0.f;

    #pragma unroll
    for (int i = 0; i < K; ++i) {
        // sal row (ty+i), cols tx*4 .. tx*4+9 cover all j in 0..6 for 4 pixels
        float row[K + 3];
        #pragma unroll
        for (int c = 0; c < K + 3; ++c)
            row[c] = sal[ty + i][tx * 4 + c];

        #pragma unroll
        for (int j = 0; j < K; ++j) {
            const int n = i * K + j;
            const float4 c4 =
                *reinterpret_cast<const float4*>(&coeff[cbase + (size_t)n * HW]);
            acc0 = fmaf(row[j + 0], c4.x, acc0);
            acc1 = fmaf(row[j + 1], c4.y, acc1);
            acc2 = fmaf(row[j + 2], c4.z, acc2);
            acc3 = fmaf(row[j + 3], c4.w, acc3);
        }
    }

    const float4 o = make_float4(acc0, acc1, acc2, acc3);
    *reinterpret_cast<float4*>(&out[base1 + (size_t)h * W + w]) = o;
}

extern "C" void kernel_launch(void* const* d_in, const int* in_sizes, int n_in,
                              void* d_out, int out_size, void* d_ws, size_t ws_size,
                              hipStream_t stream) {
    const float* thick = (const float*)d_in[0];
    const float* thin  = (const float*)d_in[1];
    const float* coeff = (const float*)d_in[2];
    float* out = (float*)d_out;

    const int H = 512, W = 512;
    const int B = in_sizes[0] / (H * W);   // 8

    dim3 grid(W / TW, H / TH, B);          // (4, 64, 8) = 2048 blocks
    dim3 block(32, 8);                     // 256 threads, 4 waves

    hipLaunchKernelGGL(adaptive_aggregation_kernel, grid, block, 0, stream,
                       thick, thin, coeff, out, H, W);
}

// Round 2
// 513.545 us; speedup vs baseline: 1.0504x; 1.0504x over previous
//
#include <hip/hip_runtime.h>

#define K 7
#define PAD 3
#define TW 512                 // full row width
#define TH 8                   // tile height (pixels)
#define LW (TW + 2 * PAD)      // 518 staged cols
#define LH (TH + 2 * PAD)      // 14 staged rows
#define LSTRIDE 520            // float stride; 520 % 32 = 8 -> rows rotate banks

typedef float f32x4 __attribute__((ext_vector_type(4)));

__global__ __launch_bounds__(1024) void adaptive_aggregation_kernel(
    const float* __restrict__ thick,
    const float* __restrict__ thin,
    const float* __restrict__ coeff,
    float* __restrict__ out,
    int H, int W)
{
    __shared__ float sal[LH][LSTRIDE];   // 14 x 520 x 4B = 29.1 KB

    const int b  = blockIdx.y;
    const int h0 = blockIdx.x * TH;
    const int tx = threadIdx.x;          // 0..127
    const int ty = threadIdx.y;          // 0..7
    const int tid = ty * 128 + tx;       // 0..1023
    const int HW = H * W;
    const size_t base1 = (size_t)b * HW;

    // ---- stage sal = max(thick, thin) stripe + vertical halo into LDS ----
    for (int idx = tid; idx < LH * LW; idx += 1024) {
        const int lr = idx / LW;
        const int lc = idx - lr * LW;
        const int gh = h0 - PAD + lr;
        const int gw = lc - PAD;
        float v = 0.0f;
        if (gh >= 0 && gh < H && gw >= 0 && gw < W) {
            const size_t off = base1 + (size_t)gh * W + gw;
            v = fmaxf(thick[off], thin[off]);
        }
        sal[lr][lc] = v;
    }
    __syncthreads();

    // ---- each thread: 4 consecutive output pixels at (h0+ty, tx*4 ..+3) ----
    const int h = h0 + ty;
    const int w = tx * 4;
    const float* cptr = coeff + (size_t)b * (K * K) * HW + (size_t)h * W + w;

    float acc0 = 0.f, acc1 = 0.f, acc2 = 0.f, acc3 = 0.f;

    #pragma unroll
    for (int i = 0; i < K; ++i) {
        // sal row (ty+i), cols w .. w+9 cover all j in 0..6 for the 4 pixels
        float row[K + 3];
        #pragma unroll
        for (int c = 0; c < K + 3; ++c)
            row[c] = sal[ty + i][w + c];

        #pragma unroll
        for (int j = 0; j < K; ++j) {
            const int n = i * K + j;
            const f32x4 c4 = __builtin_nontemporal_load(
                reinterpret_cast<const f32x4*>(cptr + (size_t)n * HW));
            acc0 = fmaf(row[j + 0], c4.x, acc0);
            acc1 = fmaf(row[j + 1], c4.y, acc1);
            acc2 = fmaf(row[j + 2], c4.z, acc2);
            acc3 = fmaf(row[j + 3], c4.w, acc3);
        }
    }

    f32x4 o;
    o.x = acc0; o.y = acc1; o.z = acc2; o.w = acc3;
    __builtin_nontemporal_store(
        o, reinterpret_cast<f32x4*>(out + base1 + (size_t)h * W + w));
}

extern "C" void kernel_launch(void* const* d_in, const int* in_sizes, int n_in,
                              void* d_out, int out_size, void* d_ws, size_t ws_size,
                              hipStream_t stream) {
    const float* thick = (const float*)d_in[0];
    const float* thin  = (const float*)d_in[1];
    const float* coeff = (const float*)d_in[2];
    float* out = (float*)d_out;

    const int H = 512, W = 512;
    const int B = in_sizes[0] / (H * W);   // 8

    dim3 grid(H / TH, B);                  // (64, 8) = 512 blocks, 2/CU
    dim3 block(128, 8);                    // 1024 threads = 16 waves

    hipLaunchKernelGGL(adaptive_aggregation_kernel, grid, block, 0, stream,
                       thick, thin, coeff, out, H, W);
}